// Round 7
// baseline (165.496 us; speedup 1.0000x reference)
//
#include <hip/hip_runtime.h>
#include <hip/hip_bf16.h>

#define BATCH 4
#define SEQ   4096
#define DIM   64
#define TK    64               // keys per LDS tile
#define TOTQ  (BATCH * SEQ)    // 16384
#define LOG2E 1.4426950408889634f

#if __has_builtin(__builtin_amdgcn_mfma_f32_16x16x16bf16_1k)
#define HAVE_1K 1
#else
#define HAVE_1K 0              // inline-asm v_mfma_f32_16x16x16_bf16 (ISA-confirmed gfx950)
#endif

#if __has_builtin(__builtin_amdgcn_exp2f)
#define EXP2(x) __builtin_amdgcn_exp2f(x)
#else
#define EXP2(x) exp2f(x)
#endif

typedef __attribute__((ext_vector_type(8))) short bf16x8;   // 4 VGPR frag (x32 MFMA A/B)
typedef __attribute__((ext_vector_type(4))) short bf16x4;   // 2 VGPR frag (x16 MFMA A/B)
typedef __attribute__((ext_vector_type(4))) float f32x4;    // MFMA C/D frag

#define AS1 __attribute__((address_space(1)))
#define AS3 __attribute__((address_space(3)))

static __device__ __forceinline__ short f2bf(float x) {
    __hip_bfloat16 h = __float2bfloat16(x);
    return *reinterpret_cast<short*>(&h);
}
static __device__ __forceinline__ float bf2f(short s) {
    unsigned int u = ((unsigned int)(unsigned short)s) << 16;
    float f; __builtin_memcpy(&f, &u, 4); return f;
}
static __device__ __forceinline__ int pk2bf(float lo, float hi) {
    __hip_bfloat162 t = __float22bfloat162_rn(make_float2(lo, hi));
    int r; __builtin_memcpy(&r, &t, 4); return r;
}
static __device__ __forceinline__ bf16x4 mk4(const f32x4& s) {
    int2 t = make_int2(pk2bf(s[0], s[1]), pk2bf(s[2], s[3]));
    bf16x4 r; __builtin_memcpy(&r, &t, 8); return r;
}
static __device__ __forceinline__ f32x4 mfma16(bf16x4 a, bf16x4 b, f32x4 c) {
#if HAVE_1K
    return __builtin_amdgcn_mfma_f32_16x16x16bf16_1k(a, b, c, 0, 0, 0);
#else
    asm("v_mfma_f32_16x16x16_bf16 %0, %1, %2, %0" : "+v"(c) : "v"(a), "v"(b));
    return c;
#endif
}
static __device__ __forceinline__ void async16(const short* g, short* l) {
    __builtin_amdgcn_global_load_lds((const AS1 unsigned int*)g,
                                     (AS3 unsigned int*)l, 16, 0, 0);
}

// ---------------- pack pre-pass (identical to R6 — proven) ----------------
__global__ __launch_bounds__(256)
void pack_kv(const float* __restrict__ kg, const float* __restrict__ vg,
             const float* __restrict__ mg,
             short* __restrict__ kp, short* __restrict__ vtp)
{
    if (blockIdx.x < 256) {                            // ---- K: 4 float4 / thread ----
        #pragma unroll
        for (int i = 0; i < 4; ++i) {
            const int unit = blockIdx.x * 1024 + i * 256 + threadIdx.x;
            const int row = unit >> 4;
            const int d0  = (unit & 15) * 4;
            f32x4 kv = *reinterpret_cast<const f32x4*>(kg + (size_t)row * DIM + d0);
            short4 ks;
            ks.x = f2bf(kv[0]); ks.y = f2bf(kv[1]); ks.z = f2bf(kv[2]); ks.w = f2bf(kv[3]);
            const int gs = (d0 >> 3) ^ (row & 7);
            *reinterpret_cast<short4*>(kp + (size_t)row * DIM + gs * 8 + (d0 & 7)) = ks;
        }
    } else {                                           // ---- V: one 64-key tile / block ----
        __shared__ float Vl[64][66];
        __shared__ float Ml[64];
        const int tile = blockIdx.x - 256;
        const float* src = vg + (size_t)tile * TK * DIM;
        const int tid = threadIdx.x;
        #pragma unroll
        for (int i = 0; i < 4; ++i) {
            int idx = i * 256 + tid;
            int key = idx >> 4, part = idx & 15;
            f32x4 vv = *reinterpret_cast<const f32x4*>(src + (size_t)key * DIM + part * 4);
            float2* p0 = reinterpret_cast<float2*>(&Vl[key][part * 4]);
            p0[0] = make_float2(vv[0], vv[1]);
            p0[1] = make_float2(vv[2], vv[3]);
        }
        if (tid < 64) Ml[tid] = mg[(size_t)tile * TK + tid];
        __syncthreads();
        #pragma unroll
        for (int i = 0; i < 2; ++i) {
            const int gid = i * 256 + tid;
            const int d = gid >> 3;
            const int G = gid & 7;           // G = qd*2 + u
            const int qd = G >> 1, u = G & 1;
            alignas(16) short s8[8];
            #pragma unroll
            for (int e = 0; e < 8; ++e) {    // e = v*4 + j
                const int v = e >> 2, j = e & 3;
                const int key = (2 * u + v) * 16 + qd * 4 + j;
                s8[e] = f2bf(Vl[key][d] * Ml[key]);
            }
            const int Gs = G ^ (d & 7);
            short* dst = vtp + (size_t)tile * (TK * DIM) + d * TK + Gs * 8;
            *reinterpret_cast<int4*>(dst) = *reinterpret_cast<const int4*>(s8);
        }
    }
}

// ---------------- main attention kernel (R6 core + fused split-K combine) --------
// S^T orientation; Q pre-scaled 0.125*log2e so p = exp2(s); V pre-masked;
// PV via 16x16x16 MFMA (S^T C-layout == P^T B-layout, no cross-lane move).
// NSEG>1: bf16 partial O + fp32 l to ws; LAST seg-block per (b,qblk) ticket
// (device-scope fence+atomic) reduces and writes the final output.
template<int NSEG>
__global__ __launch_bounds__(256, 4)
void attn_fwd7(const float* __restrict__ qg, const float* __restrict__ mg,
               const short* __restrict__ kp, const short* __restrict__ vtp,
               float* __restrict__ outg,
               short* __restrict__ Opart, float* __restrict__ lpart,
               int* __restrict__ cnt)
{
    constexpr int SEGLEN = SEQ / NSEG;
    constexpr int ITERS  = SEGLEN / TK;

    __shared__ __align__(16) short Kl[2][TK][DIM];   // 2 x 8 KB
    __shared__ __align__(16) short Vt[2][DIM][TK];   // 2 x 8 KB
    __shared__ int sOld;

    const int tid  = threadIdx.x;
    const int wave = tid >> 6;
    const int lane = tid & 63;
    const int ln   = lane & 15;
    const int quad = lane >> 4;

    const int qblk = blockIdx.x & 31;                // 32 q-blocks of 128 rows
    const int rest = blockIdx.x >> 5;
    const int seg  = (NSEG == 1) ? 0 : (rest & (NSEG - 1));
    const int b    = (NSEG == 1) ? rest : (rest / NSEG);

    const int qw = qblk * 128 + wave * 32;           // wave's first q row
    const size_t bbase = (size_t)b * SEQ * DIM;

    const short* kb  = kp  + bbase + (size_t)seg * SEGLEN * DIM;
    const short* vb  = vtp + bbase + (size_t)seg * SEGLEN * DIM;
    const float* mgb = mg + (size_t)b * SEQ;

    const int gs0 = quad ^ (ln & 7);                 // K-frag granule (h=0); h=1: ^4

    // loop-invariant Q B-frags (x32 QK): B[k=quad*8+j][n=ln], scale 0.125*log2e
    bf16x8 aq[2][2];
    #pragma unroll
    for (int qt = 0; qt < 2; ++qt) {
        const float* qrow = qg + bbase + (size_t)(qw + qt * 16 + ln) * DIM;
        #pragma unroll
        for (int h = 0; h < 2; ++h) {
            alignas(16) short tmp[8];
            #pragma unroll
            for (int j = 0; j < 8; ++j)
                tmp[j] = f2bf(qrow[quad * 8 + h * 32 + j] * (0.125f * LOG2E));
            aq[qt][h] = *reinterpret_cast<bf16x8*>(tmp);
        }
    }

    f32x4 O[2][4];               // [q-tile][ds]; lane: d = ds*16+quad*4+r, q = qw+qt*16+ln
    float lacc[2] = {0.f, 0.f};
    #pragma unroll
    for (int qt = 0; qt < 2; ++qt)
        #pragma unroll
        for (int i = 0; i < 4; ++i) O[qt][i] = (f32x4){0.f, 0.f, 0.f, 0.f};

    // prologue DMA: tile 0 -> buf 0
    #pragma unroll
    for (int i = 0; i < 2; ++i) {
        const int c = wave * 2 + i;
        async16(kb + c * 512 + lane * 8, &Kl[0][0][0] + c * 512);
        async16(vb + c * 512 + lane * 8, &Vt[0][0][0] + c * 512);
    }

    for (int t = 0; t < ITERS; ++t) {
        const int buf = t & 1;
        asm volatile("s_waitcnt vmcnt(0)" ::: "memory");
        __syncthreads();

        if (t + 1 < ITERS) {
            const short* gk = kb + (size_t)(t + 1) * TK * DIM;
            const short* gv = vb + (size_t)(t + 1) * TK * DIM;
            #pragma unroll
            for (int i = 0; i < 2; ++i) {
                const int c = wave * 2 + i;
                async16(gk + c * 512 + lane * 8, &Kl[buf ^ 1][0][0] + c * 512);
                async16(gv + c * 512 + lane * 8, &Vt[buf ^ 1][0][0] + c * 512);
            }
        }

        const int key0 = seg * SEGLEN + t * TK;
        const short* klb = &Kl[buf][0][0];
        const short* vtb = &Vt[buf][0][0];

        #pragma unroll
        for (int u = 0; u < 2; ++u) {
            f32x4 m4[2];
            #pragma unroll
            for (int v = 0; v < 2; ++v)
                m4[v] = *reinterpret_cast<const f32x4*>(
                    mgb + key0 + (2 * u + v) * 16 + quad * 4);

            // ---- K.Q^T ----
            f32x4 sf[2][2];
            #pragma unroll
            for (int v = 0; v < 2; ++v) {
                const int s = 2 * u + v;
                bf16x8 ka0 = *reinterpret_cast<const bf16x8*>(
                    klb + (s * 16 + ln) * DIM + gs0 * 8);
                bf16x8 ka1 = *reinterpret_cast<const bf16x8*>(
                    klb + (s * 16 + ln) * DIM + (gs0 ^ 4) * 8);
                #pragma unroll
                for (int qt = 0; qt < 2; ++qt) {
                    f32x4 acc = (f32x4){0.f, 0.f, 0.f, 0.f};
                    acc = __builtin_amdgcn_mfma_f32_16x16x32_bf16(ka0, aq[qt][0], acc, 0, 0, 0);
                    acc = __builtin_amdgcn_mfma_f32_16x16x32_bf16(ka1, aq[qt][1], acc, 0, 0, 0);
                    sf[qt][v] = acc;
                }
            }

            // ---- p = exp2(s); l += p*mask; pack ----
            bf16x4 bp[2][2];
            #pragma unroll
            for (int qt = 0; qt < 2; ++qt) {
                #pragma unroll
                for (int v = 0; v < 2; ++v) {
                    #pragma unroll
                    for (int r = 0; r < 4; ++r) {
                        sf[qt][v][r] = EXP2(sf[qt][v][r]);
                        lacc[qt] = fmaf(sf[qt][v][r], m4[v][r], lacc[qt]);
                    }
                    bp[qt][v] = mk4(sf[qt][v]);
                }
            }

            // ---- PV ----
            const int gvu = (quad * 2 + u) ^ (ln & 7);
            #pragma unroll
            for (int ds = 0; ds < 4; ++ds) {
                bf16x8 vf = *reinterpret_cast<const bf16x8*>(
                    vtb + (ds * 16 + ln) * TK + gvu * 8);
                bf16x4 va0 = __builtin_shufflevector(vf, vf, 0, 1, 2, 3);
                bf16x4 va1 = __builtin_shufflevector(vf, vf, 4, 5, 6, 7);
                #pragma unroll
                for (int qt = 0; qt < 2; ++qt) {
                    O[qt][ds] = mfma16(va0, bp[qt][0], O[qt][ds]);
                    O[qt][ds] = mfma16(va1, bp[qt][1], O[qt][ds]);
                }
            }
        }
    }

    // ---- epilogue ----
    #pragma unroll
    for (int qt = 0; qt < 2; ++qt) {
        lacc[qt] += __shfl_xor(lacc[qt], 16);
        lacc[qt] += __shfl_xor(lacc[qt], 32);
    }

    if (NSEG == 1) {
        #pragma unroll
        for (int qt = 0; qt < 2; ++qt) {
            const int qrow_i = qw + qt * 16 + ln;
            const float qm = mgb[qrow_i];
            const float inv = 1.0f / lacc[qt];
            const float* qrow = qg + bbase + (size_t)qrow_i * DIM;
            float* orow = outg + bbase + (size_t)qrow_i * DIM;
            #pragma unroll
            for (int ds = 0; ds < 4; ++ds) {
                const int d0 = ds * 16 + quad * 4;
                f32x4 o4;
                #pragma unroll
                for (int r = 0; r < 4; ++r) o4[r] = O[qt][ds][r] * inv;
                if (qm == 0.0f) {
                    f32x4 q4 = *reinterpret_cast<const f32x4*>(qrow + d0);
                    #pragma unroll
                    for (int r = 0; r < 4; ++r) o4[r] = q4[r] * 0.125f;
                }
                *reinterpret_cast<f32x4*>(orow + d0) = o4;
            }
        }
        return;
    }

    // ---- bf16 partial O + fp32 l ----
    #pragma unroll
    for (int qt = 0; qt < 2; ++qt) {
        const int gq = b * SEQ + qw + qt * 16 + ln;
        short* ob = Opart + ((size_t)seg * TOTQ + gq) * 64;
        #pragma unroll
        for (int ds = 0; ds < 4; ++ds) {
            bf16x4 o4 = mk4(O[qt][ds]);
            *reinterpret_cast<bf16x4*>(ob + ds * 16 + quad * 4) = o4;
        }
        if (quad == 0) lpart[(size_t)seg * TOTQ + gq] = lacc[qt];
    }

    // ---- ticket: last seg-block per (b,qblk) combines ----
    __syncthreads();                          // all block stores complete (vmcnt drained)
    if (tid == 0) {
        __threadfence();                      // release: make partials device-visible
        sOld = atomicAdd(cnt + (b * 32 + qblk), 1);
    }
    __syncthreads();
    if (sOld != NSEG - 1) return;

    __threadfence();                          // acquire: invalidate stale L1/L2
    const int qbase = b * SEQ + qblk * 128;
    #pragma unroll
    for (int it = 0; it < 8; ++it) {
        const int idx = it * 256 + tid;       // 2048 float4-units (128 q x 16)
        const int qo  = idx >> 4;
        const int d0  = (idx & 15) * 4;
        const int gq  = qbase + qo;
        float a0 = 0.f, a1 = 0.f, a2 = 0.f, a3 = 0.f, den = 0.f;
        #pragma unroll
        for (int s = 0; s < NSEG; ++s) {
            const short* ob = Opart + ((size_t)s * TOTQ + gq) * 64 + d0;
            short4 o4 = *reinterpret_cast<const short4*>(ob);
            a0 += bf2f(o4.x); a1 += bf2f(o4.y);
            a2 += bf2f(o4.z); a3 += bf2f(o4.w);
            den += lpart[(size_t)s * TOTQ + gq];
        }
        const float inv = 1.0f / den;
        f32x4 o;
        o[0] = a0 * inv; o[1] = a1 * inv; o[2] = a2 * inv; o[3] = a3 * inv;
        if (mg[gq] == 0.0f) {
            f32x4 q4 = *reinterpret_cast<const f32x4*>(qg + (size_t)gq * DIM + d0);
            #pragma unroll
            for (int r = 0; r < 4; ++r) o[r] = q4[r] * 0.125f;
        }
        *reinterpret_cast<f32x4*>(outg + (size_t)gq * DIM + d0) = o;
    }
}

extern "C" void kernel_launch(void* const* d_in, const int* in_sizes, int n_in,
                              void* d_out, int out_size, void* d_ws, size_t ws_size,
                              hipStream_t stream) {
    (void)in_sizes; (void)n_in; (void)out_size;
    const float* q = (const float*)d_in[0];
    const float* k = (const float*)d_in[1];
    const float* v = (const float*)d_in[2];
    const float* m = (const float*)d_in[3];
    float* out = (float*)d_out;

    const size_t nelem  = (size_t)BATCH * SEQ * DIM;            // 1M
    const size_t packsz = nelem * 2 * sizeof(short);            // 4 MB
    const size_t osz    = (size_t)8 * TOTQ * 64 * sizeof(short);// 16 MB
    const size_t lsz    = (size_t)8 * TOTQ * sizeof(float);     // 512 KB
    const size_t csz    = 512;                                  // 128 counters

    short* kp   = (short*)d_ws;
    short* vtp  = kp + nelem;
    short* Op   = (short*)((char*)d_ws + packsz);
    float* lp   = (float*)((char*)d_ws + packsz + osz);
    int*   cnt  = (int*)  ((char*)d_ws + packsz + osz + lsz);

    if (ws_size >= packsz + osz + lsz + csz) {
        hipMemsetAsync(cnt, 0, csz, stream);
        pack_kv<<<dim3(512), dim3(256), 0, stream>>>(k, v, m, kp, vtp);
        attn_fwd7<8><<<dim3(BATCH * 32 * 8), dim3(256), 0, stream>>>(
            q, m, kp, vtp, out, Op, lp, cnt);
    } else {
        pack_kv<<<dim3(512), dim3(256), 0, stream>>>(k, v, m, kp, vtp);
        attn_fwd7<1><<<dim3(BATCH * 32), dim3(256), 0, stream>>>(
            q, m, kp, vtp, out, nullptr, nullptr, nullptr);
    }
}

// Round 8
// 104.929 us; speedup vs baseline: 1.5772x; 1.5772x over previous
//
#include <hip/hip_runtime.h>
#include <hip/hip_bf16.h>

#define BATCH 4
#define SEQ   4096
#define DIM   64
#define TK    64               // keys per LDS tile
#define TOTQ  (BATCH * SEQ)    // 16384
#define LOG2E 1.4426950408889634f

#if __has_builtin(__builtin_amdgcn_mfma_f32_16x16x16bf16_1k)
#define HAVE_1K 1
#else
#define HAVE_1K 0              // inline-asm v_mfma_f32_16x16x16_bf16 (ISA-confirmed gfx950)
#endif

#if __has_builtin(__builtin_amdgcn_exp2f)
#define EXP2(x) __builtin_amdgcn_exp2f(x)
#else
#define EXP2(x) exp2f(x)
#endif

typedef __attribute__((ext_vector_type(8))) short bf16x8;   // 4 VGPR frag (x32 MFMA A/B)
typedef __attribute__((ext_vector_type(4))) short bf16x4;   // 2 VGPR frag (x16 MFMA A/B)
typedef __attribute__((ext_vector_type(4))) float f32x4;    // MFMA C/D frag

#define AS1 __attribute__((address_space(1)))
#define AS3 __attribute__((address_space(3)))

static __device__ __forceinline__ short f2bf(float x) {
    __hip_bfloat16 h = __float2bfloat16(x);
    return *reinterpret_cast<short*>(&h);
}
static __device__ __forceinline__ float bf2f(short s) {
    unsigned int u = ((unsigned int)(unsigned short)s) << 16;
    float f; __builtin_memcpy(&f, &u, 4); return f;
}
static __device__ __forceinline__ int pk2bf(float lo, float hi) {
    __hip_bfloat162 t = __float22bfloat162_rn(make_float2(lo, hi));
    int r; __builtin_memcpy(&r, &t, 4); return r;
}
static __device__ __forceinline__ bf16x4 mk4(const f32x4& s) {
    int2 t = make_int2(pk2bf(s[0], s[1]), pk2bf(s[2], s[3]));
    bf16x4 r; __builtin_memcpy(&r, &t, 8); return r;
}
static __device__ __forceinline__ f32x4 mfma16(bf16x4 a, bf16x4 b, f32x4 c) {
#if HAVE_1K
    return __builtin_amdgcn_mfma_f32_16x16x16bf16_1k(a, b, c, 0, 0, 0);
#else
    asm("v_mfma_f32_16x16x16_bf16 %0, %1, %2, %0" : "+v"(c) : "v"(a), "v"(b));
    return c;
#endif
}
static __device__ __forceinline__ void async16(const short* g, short* l) {
    __builtin_amdgcn_global_load_lds((const AS1 unsigned int*)g,
                                     (AS3 unsigned int*)l, 16, 0, 0);
}

// ---------------- pack pre-pass (identical to R6 — proven) ----------------
__global__ __launch_bounds__(256)
void pack_kv(const float* __restrict__ kg, const float* __restrict__ vg,
             const float* __restrict__ mg,
             short* __restrict__ kp, short* __restrict__ vtp)
{
    if (blockIdx.x < 256) {                            // ---- K: 4 float4 / thread ----
        #pragma unroll
        for (int i = 0; i < 4; ++i) {
            const int unit = blockIdx.x * 1024 + i * 256 + threadIdx.x;
            const int row = unit >> 4;
            const int d0  = (unit & 15) * 4;
            f32x4 kv = *reinterpret_cast<const f32x4*>(kg + (size_t)row * DIM + d0);
            short4 ks;
            ks.x = f2bf(kv[0]); ks.y = f2bf(kv[1]); ks.z = f2bf(kv[2]); ks.w = f2bf(kv[3]);
            const int gs = (d0 >> 3) ^ (row & 7);
            *reinterpret_cast<short4*>(kp + (size_t)row * DIM + gs * 8 + (d0 & 7)) = ks;
        }
    } else {                                           // ---- V: one 64-key tile / block ----
        __shared__ float Vl[64][66];
        __shared__ float Ml[64];
        const int tile = blockIdx.x - 256;
        const float* src = vg + (size_t)tile * TK * DIM;
        const int tid = threadIdx.x;
        #pragma unroll
        for (int i = 0; i < 4; ++i) {
            int idx = i * 256 + tid;
            int key = idx >> 4, part = idx & 15;
            f32x4 vv = *reinterpret_cast<const f32x4*>(src + (size_t)key * DIM + part * 4);
            float2* p0 = reinterpret_cast<float2*>(&Vl[key][part * 4]);
            p0[0] = make_float2(vv[0], vv[1]);
            p0[1] = make_float2(vv[2], vv[3]);
        }
        if (tid < 64) Ml[tid] = mg[(size_t)tile * TK + tid];
        __syncthreads();
        #pragma unroll
        for (int i = 0; i < 2; ++i) {
            const int gid = i * 256 + tid;
            const int d = gid >> 3;
            const int G = gid & 7;           // G = qd*2 + u
            const int qd = G >> 1, u = G & 1;
            alignas(16) short s8[8];
            #pragma unroll
            for (int e = 0; e < 8; ++e) {    // e = v*4 + j
                const int v = e >> 2, j = e & 3;
                const int key = (2 * u + v) * 16 + qd * 4 + j;
                s8[e] = f2bf(Vl[key][d] * Ml[key]);
            }
            const int Gs = G ^ (d & 7);
            short* dst = vtp + (size_t)tile * (TK * DIM) + d * TK + Gs * 8;
            *reinterpret_cast<int4*>(dst) = *reinterpret_cast<const int4*>(s8);
        }
    }
}

// ---------------- main attention kernel (R6 core; bf16 partials) ----------------
// S^T orientation; Q pre-scaled 0.125*log2e so p = exp2(s); V pre-masked;
// PV via 16x16x16 MFMA (S^T C-layout == P^T B-layout, no cross-lane move).
template<int NSEG>
__global__ __launch_bounds__(256, 4)
void attn_fwd8(const float* __restrict__ qg, const float* __restrict__ mg,
               const short* __restrict__ kp, const short* __restrict__ vtp,
               float* __restrict__ outg,
               short* __restrict__ Opart, float* __restrict__ lpart)
{
    constexpr int SEGLEN = SEQ / NSEG;
    constexpr int ITERS  = SEGLEN / TK;

    __shared__ __align__(16) short Kl[2][TK][DIM];   // 2 x 8 KB
    __shared__ __align__(16) short Vt[2][DIM][TK];   // 2 x 8 KB

    const int tid  = threadIdx.x;
    const int wave = tid >> 6;
    const int lane = tid & 63;
    const int ln   = lane & 15;
    const int quad = lane >> 4;

    const int qblk = blockIdx.x & 31;                // 32 q-blocks of 128 rows
    const int rest = blockIdx.x >> 5;
    const int seg  = (NSEG == 1) ? 0 : (rest & (NSEG - 1));
    const int b    = (NSEG == 1) ? rest : (rest / NSEG);

    const int qw = qblk * 128 + wave * 32;           // wave's first q row
    const size_t bbase = (size_t)b * SEQ * DIM;

    const short* kb  = kp  + bbase + (size_t)seg * SEGLEN * DIM;
    const short* vb  = vtp + bbase + (size_t)seg * SEGLEN * DIM;
    const float* mgb = mg + (size_t)b * SEQ;

    const int gs0 = quad ^ (ln & 7);                 // K-frag granule (h=0); h=1: ^4

    // loop-invariant Q B-frags (x32 QK): B[k=quad*8+j][n=ln], scale 0.125*log2e
    bf16x8 aq[2][2];
    #pragma unroll
    for (int qt = 0; qt < 2; ++qt) {
        const float* qrow = qg + bbase + (size_t)(qw + qt * 16 + ln) * DIM;
        #pragma unroll
        for (int h = 0; h < 2; ++h) {
            alignas(16) short tmp[8];
            #pragma unroll
            for (int j = 0; j < 8; ++j)
                tmp[j] = f2bf(qrow[quad * 8 + h * 32 + j] * (0.125f * LOG2E));
            aq[qt][h] = *reinterpret_cast<bf16x8*>(tmp);
        }
    }

    f32x4 O[2][4];               // [q-tile][ds]; lane: d = ds*16+quad*4+r, q = qw+qt*16+ln
    float lacc[2] = {0.f, 0.f};
    #pragma unroll
    for (int qt = 0; qt < 2; ++qt)
        #pragma unroll
        for (int i = 0; i < 4; ++i) O[qt][i] = (f32x4){0.f, 0.f, 0.f, 0.f};

    // prologue DMA: tile 0 -> buf 0
    #pragma unroll
    for (int i = 0; i < 2; ++i) {
        const int c = wave * 2 + i;
        async16(kb + c * 512 + lane * 8, &Kl[0][0][0] + c * 512);
        async16(vb + c * 512 + lane * 8, &Vt[0][0][0] + c * 512);
    }

    for (int t = 0; t < ITERS; ++t) {
        const int buf = t & 1;
        asm volatile("s_waitcnt vmcnt(0)" ::: "memory");
        __syncthreads();

        if (t + 1 < ITERS) {
            const short* gk = kb + (size_t)(t + 1) * TK * DIM;
            const short* gv = vb + (size_t)(t + 1) * TK * DIM;
            #pragma unroll
            for (int i = 0; i < 2; ++i) {
                const int c = wave * 2 + i;
                async16(gk + c * 512 + lane * 8, &Kl[buf ^ 1][0][0] + c * 512);
                async16(gv + c * 512 + lane * 8, &Vt[buf ^ 1][0][0] + c * 512);
            }
        }

        const int key0 = seg * SEGLEN + t * TK;
        const short* klb = &Kl[buf][0][0];
        const short* vtb = &Vt[buf][0][0];

        #pragma unroll
        for (int u = 0; u < 2; ++u) {
            f32x4 m4[2];
            #pragma unroll
            for (int v = 0; v < 2; ++v)
                m4[v] = *reinterpret_cast<const f32x4*>(
                    mgb + key0 + (2 * u + v) * 16 + quad * 4);

            // ---- K.Q^T ----
            f32x4 sf[2][2];
            #pragma unroll
            for (int v = 0; v < 2; ++v) {
                const int s = 2 * u + v;
                bf16x8 ka0 = *reinterpret_cast<const bf16x8*>(
                    klb + (s * 16 + ln) * DIM + gs0 * 8);
                bf16x8 ka1 = *reinterpret_cast<const bf16x8*>(
                    klb + (s * 16 + ln) * DIM + (gs0 ^ 4) * 8);
                #pragma unroll
                for (int qt = 0; qt < 2; ++qt) {
                    f32x4 acc = (f32x4){0.f, 0.f, 0.f, 0.f};
                    acc = __builtin_amdgcn_mfma_f32_16x16x32_bf16(ka0, aq[qt][0], acc, 0, 0, 0);
                    acc = __builtin_amdgcn_mfma_f32_16x16x32_bf16(ka1, aq[qt][1], acc, 0, 0, 0);
                    sf[qt][v] = acc;
                }
            }

            // ---- p = exp2(s); l += p*mask; pack ----
            bf16x4 bp[2][2];
            #pragma unroll
            for (int qt = 0; qt < 2; ++qt) {
                #pragma unroll
                for (int v = 0; v < 2; ++v) {
                    #pragma unroll
                    for (int r = 0; r < 4; ++r) {
                        sf[qt][v][r] = EXP2(sf[qt][v][r]);
                        lacc[qt] = fmaf(sf[qt][v][r], m4[v][r], lacc[qt]);
                    }
                    bp[qt][v] = mk4(sf[qt][v]);
                }
            }

            // ---- PV ----
            const int gvu = (quad * 2 + u) ^ (ln & 7);
            #pragma unroll
            for (int ds = 0; ds < 4; ++ds) {
                bf16x8 vf = *reinterpret_cast<const bf16x8*>(
                    vtb + (ds * 16 + ln) * TK + gvu * 8);
                bf16x4 va0 = __builtin_shufflevector(vf, vf, 0, 1, 2, 3);
                bf16x4 va1 = __builtin_shufflevector(vf, vf, 4, 5, 6, 7);
                #pragma unroll
                for (int qt = 0; qt < 2; ++qt) {
                    O[qt][ds] = mfma16(va0, bp[qt][0], O[qt][ds]);
                    O[qt][ds] = mfma16(va1, bp[qt][1], O[qt][ds]);
                }
            }
        }
    }

    // ---- epilogue ----
    #pragma unroll
    for (int qt = 0; qt < 2; ++qt) {
        lacc[qt] += __shfl_xor(lacc[qt], 16);
        lacc[qt] += __shfl_xor(lacc[qt], 32);
    }

    if (NSEG == 1) {
        #pragma unroll
        for (int qt = 0; qt < 2; ++qt) {
            const int qrow_i = qw + qt * 16 + ln;
            const float qm = mgb[qrow_i];
            const float inv = 1.0f / lacc[qt];
            const float* qrow = qg + bbase + (size_t)qrow_i * DIM;
            float* orow = outg + bbase + (size_t)qrow_i * DIM;
            #pragma unroll
            for (int ds = 0; ds < 4; ++ds) {
                const int d0 = ds * 16 + quad * 4;
                f32x4 o4;
                #pragma unroll
                for (int r = 0; r < 4; ++r) o4[r] = O[qt][ds][r] * inv;
                if (qm == 0.0f) {
                    f32x4 q4 = *reinterpret_cast<const f32x4*>(qrow + d0);
                    #pragma unroll
                    for (int r = 0; r < 4; ++r) o4[r] = q4[r] * 0.125f;
                }
                *reinterpret_cast<f32x4*>(orow + d0) = o4;
            }
        }
    } else {
        // bf16 partial O [seg][gq][64] + fp32 l [seg][gq]
        #pragma unroll
        for (int qt = 0; qt < 2; ++qt) {
            const int gq = b * SEQ + qw + qt * 16 + ln;
            short* ob = Opart + ((size_t)seg * TOTQ + gq) * 64;
            #pragma unroll
            for (int ds = 0; ds < 2; ++ds) {
                // two 16B stores (4 x bf16x4 pairs)
                bf16x4 lo = mk4(O[qt][ds * 2 + 0]);
                bf16x4 hi = mk4(O[qt][ds * 2 + 1]);
                *reinterpret_cast<bf16x4*>(ob + (ds * 2 + 0) * 16 + quad * 4) = lo;
                *reinterpret_cast<bf16x4*>(ob + (ds * 2 + 1) * 16 + quad * 4) = hi;
            }
            if (quad == 0) lpart[(size_t)seg * TOTQ + gq] = lacc[qt];
        }
    }
}

// ---------------- combine partials (separate dispatch — no device fences) ------
template<int NSEG>
__global__ __launch_bounds__(256)
void combine_p(const short* __restrict__ Opart, const float* __restrict__ lpart,
               const float* __restrict__ qg, const float* __restrict__ mg,
               float* __restrict__ outg)
{
    const int t = blockIdx.x * 256 + threadIdx.x;   // TOTQ*16 threads, float4 each
    const int gq = t >> 4;
    const int d0 = (t & 15) * 4;
    float a0 = 0.f, a1 = 0.f, a2 = 0.f, a3 = 0.f, den = 0.f;
    #pragma unroll
    for (int s = 0; s < NSEG; ++s) {
        const short* ob = Opart + ((size_t)s * TOTQ + gq) * 64 + d0;
        short4 o4 = *reinterpret_cast<const short4*>(ob);
        a0 += bf2f(o4.x); a1 += bf2f(o4.y);
        a2 += bf2f(o4.z); a3 += bf2f(o4.w);
        den += lpart[(size_t)s * TOTQ + gq];
    }
    const float inv = 1.0f / den;
    f32x4 o;
    o[0] = a0 * inv; o[1] = a1 * inv; o[2] = a2 * inv; o[3] = a3 * inv;
    if (mg[gq] == 0.0f) {
        f32x4 q4 = *reinterpret_cast<const f32x4*>(qg + (size_t)gq * DIM + d0);
        #pragma unroll
        for (int r = 0; r < 4; ++r) o[r] = q4[r] * 0.125f;
    }
    *reinterpret_cast<f32x4*>(outg + (size_t)gq * DIM + d0) = o;
}

extern "C" void kernel_launch(void* const* d_in, const int* in_sizes, int n_in,
                              void* d_out, int out_size, void* d_ws, size_t ws_size,
                              hipStream_t stream) {
    (void)in_sizes; (void)n_in; (void)out_size;
    const float* q = (const float*)d_in[0];
    const float* k = (const float*)d_in[1];
    const float* v = (const float*)d_in[2];
    const float* m = (const float*)d_in[3];
    float* out = (float*)d_out;

    const size_t nelem  = (size_t)BATCH * SEQ * DIM;            // 1M
    const size_t packsz = nelem * 2 * sizeof(short);            // 4 MB
    const size_t osz    = (size_t)8 * TOTQ * 64 * sizeof(short);// 16 MB
    const size_t lsz    = (size_t)8 * TOTQ * sizeof(float);     // 512 KB

    short* kp  = (short*)d_ws;
    short* vtp = kp + nelem;
    short* Op  = (short*)((char*)d_ws + packsz);
    float* lp  = (float*)((char*)d_ws + packsz + osz);

    pack_kv<<<dim3(512), dim3(256), 0, stream>>>(k, v, m, kp, vtp);

    if (ws_size >= packsz + osz + lsz) {
        attn_fwd8<8><<<dim3(BATCH * 32 * 8), dim3(256), 0, stream>>>(
            q, m, kp, vtp, out, Op, lp);
        combine_p<8><<<dim3(TOTQ * 16 / 256), dim3(256), 0, stream>>>(
            Op, lp, q, m, out);
    } else {
        attn_fwd8<1><<<dim3(BATCH * 32), dim3(256), 0, stream>>>(
            q, m, kp, vtp, out, nullptr, nullptr);
    }
}